// Round 1
// baseline (7558.897 us; speedup 1.0000x reference)
//
#include <hip/hip_runtime.h>
#include <math.h>

// Problem constants
#define NB 512     // batch
#define HD 512     // hidden
#define CD 64      // in channels
#define TD 168     // encode length
#define DSTEPS 24  // decoder steps
#define OUTC 64    // out channels

// Tiling for the LSTM step kernel
#define BN 32      // batch tile
#define BJ 32      // hidden-column tile (x4 gates -> 128 gate rows)
#define KT 32      // K chunk
#define PN 34      // LDS pitch for activation tile (even -> b64-aligned, 2-way bank max)
#define PG 132     // LDS pitch for weight tile (16B aligned reads)

__device__ __forceinline__ float sigmf(float x) {
    return 1.0f / (1.0f + expf(-x));
}

// One LSTM step: pre = h_in @ W_hh^T (+ x_t @ W_ih^T) + b, then gates.
// Grid: (HD/BJ, NB/BN) = (16,16); block 512 threads.
// Thread (tj,tn): tj in [0,32) = hidden col within tile, tn in [0,16) = pair of batch rows.
// Each thread owns all 4 gates of its (n, j) pairs -> gates computed in-register.
template<int HAS_X>
__global__ __launch_bounds__(512)
void lstm_step_kernel(const float* __restrict__ h_in,
                      const float* __restrict__ c_in,
                      const float* __restrict__ W_hh,   // (4H, H) row-major
                      const float* __restrict__ bias,   // (4H,)
                      const float* __restrict__ x,      // (N, C, T) or null
                      const float* __restrict__ W_ih,   // (4H, C) or null
                      int t,
                      float* __restrict__ h_out,
                      float* __restrict__ c_out)
{
    __shared__ __align__(16) float hsT[KT * PN];   // hsT[k][n]
    __shared__ __align__(16) float wsT[KT * PG];   // wsT[k][jj*4 + gate]

    const int tid = threadIdx.x;
    const int tj  = tid & 31;
    const int tn  = tid >> 5;            // 0..15
    const int j0  = blockIdx.x * BJ;
    const int n0  = blockIdx.y * BN;

    float acc[2][4] = {{0.f,0.f,0.f,0.f},{0.f,0.f,0.f,0.f}};

    const int nChunks = HD / KT + (HAS_X ? CD / KT : 0);  // 16 (+2 for encoder)
    for (int ch = 0; ch < nChunks; ++ch) {
        const int k0 = ch * KT;
        __syncthreads();
        // stage activations: 32n x 32k, transposed into hsT[k][n]
        #pragma unroll
        for (int i = 0; i < 2; ++i) {
            int e  = tid + i * 512;
            int kk = e & (KT - 1);
            int nl = e >> 5;
            int k  = k0 + kk;
            float v;
            if (!HAS_X || k < HD)
                v = h_in[(n0 + nl) * HD + k];
            else
                v = x[((n0 + nl) * CD + (k - HD)) * TD + t];
            hsT[kk * PN + nl] = v;
        }
        // stage weights: 128 gate-rows x 32k, transposed into wsT[k][jj*4+gate]
        #pragma unroll
        for (int i = 0; i < 8; ++i) {
            int e    = tid + i * 512;
            int kk   = e & 31;
            int r    = e >> 5;      // 0..127
            int gate = r >> 5;      // 0..3
            int jj   = r & 31;
            int k    = k0 + kk;
            int row  = gate * HD + j0 + jj;
            float v;
            if (!HAS_X || k < HD)
                v = W_hh[row * HD + k];
            else
                v = W_ih[row * CD + (k - HD)];
            wsT[kk * PG + jj * 4 + gate] = v;
        }
        __syncthreads();
        #pragma unroll
        for (int kk = 0; kk < KT; ++kk) {
            float a0 = hsT[kk * PN + 2 * tn];
            float a1 = hsT[kk * PN + 2 * tn + 1];
            float4 w = *reinterpret_cast<const float4*>(&wsT[kk * PG + 4 * tj]);
            acc[0][0] += a0 * w.x; acc[0][1] += a0 * w.y;
            acc[0][2] += a0 * w.z; acc[0][3] += a0 * w.w;
            acc[1][0] += a1 * w.x; acc[1][1] += a1 * w.y;
            acc[1][2] += a1 * w.z; acc[1][3] += a1 * w.w;
        }
    }

    const int j  = j0 + tj;
    const float bi = bias[0 * HD + j];
    const float bf = bias[1 * HD + j];
    const float bg = bias[2 * HD + j];
    const float bo = bias[3 * HD + j];
    #pragma unroll
    for (int i = 0; i < 2; ++i) {
        const int n = n0 + 2 * tn + i;
        float iv = acc[i][0] + bi;
        float fv = acc[i][1] + bf;
        float gv = acc[i][2] + bg;
        float ov = acc[i][3] + bo;
        float cp = c_in[n * HD + j];
        float cn = sigmf(fv) * cp + sigmf(iv) * tanhf(gv);
        float hn = sigmf(ov) * tanhf(cn);
        c_out[n * HD + j] = cn;
        h_out[n * HD + j] = hn;
    }
}

// Batched per-step dense head: out[n][o][t] = sum_k hs[t][n][k] * Wd[t][o][k] + bd[t][o]
// Grid: (NB/64, DSTEPS); block 256. Tile 64n x 64o, K=512 staged through LDS.
__global__ __launch_bounds__(256)
void dense_kernel(const float* __restrict__ hs,   // (DSTEPS, NB, HD)
                  const float* __restrict__ Wd,   // (DSTEPS, OUTC, HD)
                  const float* __restrict__ bd,   // (DSTEPS, OUTC)
                  float* __restrict__ out)        // (NB, OUTC, DSTEPS)
{
    const int t  = blockIdx.y;
    const int n0 = blockIdx.x * 64;
    const int tid = threadIdx.x;
    const int to  = tid & 15;   // 0..15 -> 4 o's each
    const int tn  = tid >> 4;   // 0..15 -> 4 n's each

    __shared__ __align__(16) float aT[32 * 68];   // aT[k][n]
    __shared__ __align__(16) float wT[32 * 68];   // wT[k][o]

    float acc[4][4] = {};

    for (int ch = 0; ch < HD / 32; ++ch) {
        const int k0 = ch * 32;
        __syncthreads();
        #pragma unroll
        for (int i = 0; i < 8; ++i) {
            int e  = tid + i * 256;
            int kk = e & 31;
            int nl = e >> 5;    // 0..63
            aT[kk * 68 + nl] = hs[((size_t)t * NB + n0 + nl) * HD + k0 + kk];
            wT[kk * 68 + nl] = Wd[((size_t)t * OUTC + nl) * HD + k0 + kk];
        }
        __syncthreads();
        #pragma unroll
        for (int kk = 0; kk < 32; ++kk) {
            float4 a = *reinterpret_cast<const float4*>(&aT[kk * 68 + tn * 4]);
            float4 w = *reinterpret_cast<const float4*>(&wT[kk * 68 + to * 4]);
            acc[0][0] += a.x * w.x; acc[0][1] += a.x * w.y; acc[0][2] += a.x * w.z; acc[0][3] += a.x * w.w;
            acc[1][0] += a.y * w.x; acc[1][1] += a.y * w.y; acc[1][2] += a.y * w.z; acc[1][3] += a.y * w.w;
            acc[2][0] += a.z * w.x; acc[2][1] += a.z * w.y; acc[2][2] += a.z * w.z; acc[2][3] += a.z * w.w;
            acc[3][0] += a.w * w.x; acc[3][1] += a.w * w.y; acc[3][2] += a.w * w.z; acc[3][3] += a.w * w.w;
        }
    }

    #pragma unroll
    for (int i = 0; i < 4; ++i) {
        #pragma unroll
        for (int jq = 0; jq < 4; ++jq) {
            int n = n0 + tn * 4 + i;
            int o = to * 4 + jq;
            out[((size_t)n * OUTC + o) * DSTEPS + t] = acc[i][jq] + bd[t * OUTC + o];
        }
    }
}

extern "C" void kernel_launch(void* const* d_in, const int* in_sizes, int n_in,
                              void* d_out, int out_size, void* d_ws, size_t ws_size,
                              hipStream_t stream) {
    const float* x       = (const float*)d_in[0];
    const float* W_ih_e  = (const float*)d_in[1];
    const float* W_hh_e  = (const float*)d_in[2];
    const float* b_e     = (const float*)d_in[3];
    const float* W_hh_d  = (const float*)d_in[4];
    const float* b_d     = (const float*)d_in[5];
    const float* W_dense = (const float*)d_in[6];
    const float* b_dense = (const float*)d_in[7];
    float* out = (float*)d_out;

    float* ws = (float*)d_ws;
    const size_t NH = (size_t)NB * HD;   // 262144 floats = 1 MB
    float* hping[2] = { ws,          ws + NH };
    float* cping[2] = { ws + 2 * NH, ws + 3 * NH };
    float* hs = ws + 4 * NH;             // DSTEPS * NH floats = 24 MB

    hipMemsetAsync(hping[0], 0, NH * sizeof(float), stream);
    hipMemsetAsync(cping[0], 0, NH * sizeof(float), stream);

    dim3 grid(HD / BJ, NB / BN);   // (16,16)
    dim3 block(512);

    // Encoder: 168 sequential steps, h/c ping-pong. 168 even -> final h,c land in slot 0.
    for (int t = 0; t < TD; ++t) {
        lstm_step_kernel<1><<<grid, block, 0, stream>>>(
            hping[t & 1], cping[t & 1], W_hh_e, b_e, x, W_ih_e, t,
            hping[(t + 1) & 1], cping[(t + 1) & 1]);
    }

    // Decoder: c starts at zero; h starts at h_enc (slot 0). h_out lands in hs[t].
    hipMemsetAsync(cping[0], 0, NH * sizeof(float), stream);
    for (int s = 0; s < DSTEPS; ++s) {
        const float* hin = (s == 0) ? hping[0] : hs + (size_t)(s - 1) * NH;
        lstm_step_kernel<0><<<grid, block, 0, stream>>>(
            hin, cping[s & 1], W_hh_d, b_d, nullptr, nullptr, 0,
            hs + (size_t)s * NH, cping[(s + 1) & 1]);
    }

    dense_kernel<<<dim3(NB / 64, DSTEPS), dim3(256), 0, stream>>>(
        hs, W_dense, b_dense, out);
}

// Round 2
// 3899.541 us; speedup vs baseline: 1.9384x; 1.9384x over previous
//
#include <hip/hip_runtime.h>
#include <math.h>

// Problem constants
#define NB 512     // batch
#define HD 512     // hidden
#define CD 64      // in channels
#define TD 168     // encode length
#define DSTEPS 24  // decoder steps
#define OUTC 64    // out channels
#define GATES 2048 // 4*HD

typedef __attribute__((ext_vector_type(8))) short bf16x8;   // 8 bf16 in 4 VGPRs
typedef __attribute__((ext_vector_type(4))) float f32x4;

__device__ __forceinline__ float sigmf(float x) { return 1.0f / (1.0f + expf(-x)); }
__device__ __forceinline__ float bf2f(unsigned short h) {
    return __uint_as_float(((unsigned)h) << 16);
}
__device__ __forceinline__ unsigned short f2bf(float x) {  // round-to-nearest-even
    unsigned u = __float_as_uint(x);
    unsigned r = (u + 0x7fffu + ((u >> 16) & 1u)) >> 16;
    return (unsigned short)r;
}

// ---------------------------------------------------------------------------
// Weight prep: split f32 weights into bf16 hi/lo planes, rows permuted so that
// output row (jt*64 + gc) holds source gate-row gate*HD + jt*16 + jj, where
// gate = (gc>>3)&3, jj = (gc&7) + 8*(gc>>5). This makes step-kernel staging a
// pure linear copy AND gives each wave all 4 gates of its j-range.
// Encoder KW=576: k<512 from W_hh, k>=512 from W_ih.
// ---------------------------------------------------------------------------
__global__ __launch_bounds__(256)
void prep_weights(const float* __restrict__ Whh, const float* __restrict__ Wih,
                  int KW, unsigned short* __restrict__ Whi, unsigned short* __restrict__ Wlo)
{
    int orow = blockIdx.x;                  // 0..2047
    int jt = orow >> 6, gc = orow & 63;
    int gate = (gc >> 3) & 3;
    int jj = (gc & 7) + ((gc >> 5) << 3);
    int srow = gate * HD + jt * 16 + jj;
    for (int k = threadIdx.x; k < KW; k += 256) {
        float v = (k < HD) ? Whh[srow * HD + k] : Wih[srow * CD + (k - HD)];
        unsigned short hi = f2bf(v);
        Whi[(size_t)orow * KW + k] = hi;
        Wlo[(size_t)orow * KW + k] = f2bf(v - bf2f(hi));
    }
}

// ---------------------------------------------------------------------------
// One LSTM step, bf16x3 MFMA. Grid (32 jtiles, 8 ntiles) = 256 blocks,
// 256 threads = 4 waves. Block tile: 64 n x 64 gate-cols (= 4 gates x 16 j).
// Wave (wn,wg) computes 32n x 32gc as 2x2 fragments of 16x16x32 MFMA.
// ---------------------------------------------------------------------------
template<int HAS_X>
__global__ __launch_bounds__(256)
void lstm_step_mfma(const unsigned short* __restrict__ h_hi,
                    const unsigned short* __restrict__ h_lo,
                    const float* __restrict__ c_in,
                    const unsigned short* __restrict__ Whi,
                    const unsigned short* __restrict__ Wlo,
                    const float* __restrict__ bias,
                    const float* __restrict__ x, int t,
                    unsigned short* __restrict__ ho_hi,
                    unsigned short* __restrict__ ho_lo,
                    float* __restrict__ c_out)
{
    constexpr int KW  = HAS_X ? (HD + CD) : HD;
    constexpr int NCH = KW / 32;

    // LDS tiles: 64 rows x 32 k bf16, pitch 40 ushorts (80B: 16B-aligned rows,
    // bank-uniform for both the staging writes and the fragment reads).
    __shared__ __align__(16) unsigned short Ah[64 * 40], Al[64 * 40];
    __shared__ __align__(16) unsigned short Bh[64 * 40], Bl[64 * 40];

    const int tid  = threadIdx.x;
    const int lane = tid & 63;
    const int wid  = tid >> 6;          // 0..3
    const int wn   = wid & 1, wg = wid >> 1;
    const int jt   = blockIdx.x;        // 0..31
    const int n0   = blockIdx.y * 64;

    const int sr = tid >> 2;            // staging row 0..63
    const int ss = tid & 3;             // staging k-slot 0..3 (8 bf16 each)

    f32x4 acc[2][2] = {};
    bf16x8 ra_h, ra_l, rb_h, rb_l;      // prefetched staging regs

    auto load_chunk = [&](int ch) {
        const int k0 = ch * 32;
        rb_h = *(const bf16x8*)&Whi[((size_t)jt * 64 + sr) * KW + k0 + ss * 8];
        rb_l = *(const bf16x8*)&Wlo[((size_t)jt * 64 + sr) * KW + k0 + ss * 8];
        if (!HAS_X || k0 < HD) {
            ra_h = *(const bf16x8*)&h_hi[(size_t)(n0 + sr) * HD + k0 + ss * 8];
            ra_l = *(const bf16x8*)&h_lo[(size_t)(n0 + sr) * HD + k0 + ss * 8];
        } else {
            const int c0 = k0 - HD + ss * 8;
            #pragma unroll
            for (int m = 0; m < 8; ++m) {
                float v = x[((size_t)(n0 + sr) * CD + c0 + m) * TD + t];
                unsigned short hi = f2bf(v);
                ra_h[m] = (short)hi;
                ra_l[m] = (short)f2bf(v - bf2f(hi));
            }
        }
    };

    load_chunk(0);
    for (int ch = 0; ch < NCH; ++ch) {
        if (ch) __syncthreads();        // prior chunk's frag reads complete
        *(bf16x8*)&Ah[sr * 40 + ss * 8] = ra_h;
        *(bf16x8*)&Al[sr * 40 + ss * 8] = ra_l;
        *(bf16x8*)&Bh[sr * 40 + ss * 8] = rb_h;
        *(bf16x8*)&Bl[sr * 40 + ss * 8] = rb_l;
        __syncthreads();
        if (ch + 1 < NCH) load_chunk(ch + 1);   // prefetch overlaps MFMAs

        const int rs = (lane >> 4) * 8;          // k-slot within row (ushorts)
        bf16x8 ah[2], al[2], bh[2], bl[2];
        #pragma unroll
        for (int fm = 0; fm < 2; ++fm) {
            int row = wn * 32 + fm * 16 + (lane & 15);
            ah[fm] = *(const bf16x8*)&Ah[row * 40 + rs];
            al[fm] = *(const bf16x8*)&Al[row * 40 + rs];
        }
        #pragma unroll
        for (int fg = 0; fg < 2; ++fg) {
            int row = wg * 32 + fg * 16 + (lane & 15);
            bh[fg] = *(const bf16x8*)&Bh[row * 40 + rs];
            bl[fg] = *(const bf16x8*)&Bl[row * 40 + rs];
        }
        #pragma unroll
        for (int fm = 0; fm < 2; ++fm)
            #pragma unroll
            for (int fg = 0; fg < 2; ++fg) {
                acc[fm][fg] = __builtin_amdgcn_mfma_f32_16x16x32_bf16(ah[fm], bh[fg], acc[fm][fg], 0, 0, 0);
                acc[fm][fg] = __builtin_amdgcn_mfma_f32_16x16x32_bf16(ah[fm], bl[fg], acc[fm][fg], 0, 0, 0);
                acc[fm][fg] = __builtin_amdgcn_mfma_f32_16x16x32_bf16(al[fm], bh[fg], acc[fm][fg], 0, 0, 0);
            }
    }

    // Epilogue. Lane holds gates {p, p+2} (p = (lane>>3)&1) for j = jt*16 + jj;
    // partner lane (lane^8) holds {1-p, 3-p}. One shfl_xor pair gathers i,f,g,o.
    const int p  = (lane >> 3) & 1;
    const int jj = (lane & 7) + (wg << 3);
    const int j  = jt * 16 + jj;
    const float b0 = bias[0 * HD + j], b1 = bias[1 * HD + j];
    const float b2 = bias[2 * HD + j], b3 = bias[3 * HD + j];
    #pragma unroll
    for (int fm = 0; fm < 2; ++fm) {
        #pragma unroll
        for (int r = 0; r < 4; ++r) {
            const int n = n0 + wn * 32 + fm * 16 + ((lane >> 4) << 2) + r;
            float v0 = acc[fm][0][r];   // gate p
            float v1 = acc[fm][1][r];   // gate p+2
            float u0 = __shfl_xor(v0, 8, 64);
            float u1 = __shfl_xor(v1, 8, 64);
            if (p == 0) {
                float gi = v0 + b0, gf = u0 + b1, gg = v1 + b2, go = u1 + b3;
                float cp = c_in[(size_t)n * HD + j];
                float cn = sigmf(gf) * cp + sigmf(gi) * tanhf(gg);
                float hn = sigmf(go) * tanhf(cn);
                c_out[(size_t)n * HD + j] = cn;
                unsigned short hh = f2bf(hn);
                ho_hi[(size_t)n * HD + j] = hh;
                ho_lo[(size_t)n * HD + j] = f2bf(hn - bf2f(hh));
            }
        }
    }
}

// ---------------------------------------------------------------------------
// Dense head: out[n][o][t] = sum_k (hs_hi+hs_lo)[t][n][k] * Wd[t][o][k] + bd.
// ---------------------------------------------------------------------------
__global__ __launch_bounds__(256)
void dense_kernel(const unsigned short* __restrict__ hs_hi,
                  const unsigned short* __restrict__ hs_lo,
                  const float* __restrict__ Wd,
                  const float* __restrict__ bd,
                  float* __restrict__ out)
{
    const int t  = blockIdx.y;
    const int n0 = blockIdx.x * 64;
    const int tid = threadIdx.x;
    const int to  = tid & 15;
    const int tn  = tid >> 4;

    __shared__ __align__(16) float aT[32 * 68];
    __shared__ __align__(16) float wT[32 * 68];

    float acc[4][4] = {};

    for (int ch = 0; ch < HD / 32; ++ch) {
        const int k0 = ch * 32;
        __syncthreads();
        #pragma unroll
        for (int i = 0; i < 8; ++i) {
            int e  = tid + i * 256;
            int kk = e & 31;
            int nl = e >> 5;
            size_t hidx = ((size_t)t * NB + n0 + nl) * HD + k0 + kk;
            aT[kk * 68 + nl] = bf2f(hs_hi[hidx]) + bf2f(hs_lo[hidx]);
            wT[kk * 68 + nl] = Wd[((size_t)t * OUTC + nl) * HD + k0 + kk];
        }
        __syncthreads();
        #pragma unroll
        for (int kk = 0; kk < 32; ++kk) {
            float4 a = *reinterpret_cast<const float4*>(&aT[kk * 68 + tn * 4]);
            float4 w = *reinterpret_cast<const float4*>(&wT[kk * 68 + to * 4]);
            acc[0][0] += a.x * w.x; acc[0][1] += a.x * w.y; acc[0][2] += a.x * w.z; acc[0][3] += a.x * w.w;
            acc[1][0] += a.y * w.x; acc[1][1] += a.y * w.y; acc[1][2] += a.y * w.z; acc[1][3] += a.y * w.w;
            acc[2][0] += a.z * w.x; acc[2][1] += a.z * w.y; acc[2][2] += a.z * w.z; acc[2][3] += a.z * w.w;
            acc[3][0] += a.w * w.x; acc[3][1] += a.w * w.y; acc[3][2] += a.w * w.z; acc[3][3] += a.w * w.w;
        }
    }

    #pragma unroll
    for (int i = 0; i < 4; ++i)
        #pragma unroll
        for (int jq = 0; jq < 4; ++jq) {
            int n = n0 + tn * 4 + i;
            int o = to * 4 + jq;
            out[((size_t)n * OUTC + o) * DSTEPS + t] = acc[i][jq] + bd[t * OUTC + o];
        }
}

// ---------------------------------------------------------------------------
extern "C" void kernel_launch(void* const* d_in, const int* in_sizes, int n_in,
                              void* d_out, int out_size, void* d_ws, size_t ws_size,
                              hipStream_t stream) {
    const float* x       = (const float*)d_in[0];
    const float* W_ih_e  = (const float*)d_in[1];
    const float* W_hh_e  = (const float*)d_in[2];
    const float* b_e     = (const float*)d_in[3];
    const float* W_hh_d  = (const float*)d_in[4];
    const float* b_d     = (const float*)d_in[5];
    const float* W_dense = (const float*)d_in[6];
    const float* b_dense = (const float*)d_in[7];
    float* out = (float*)d_out;

    const size_t NH = (size_t)NB * HD;     // 262144 elements

    char* p = (char*)d_ws;
    auto alloc = [&](size_t bytes) { char* q = p; p += (bytes + 255) & ~(size_t)255; return q; };
    float*          cping[2]; unsigned short* hhi[2]; unsigned short* hlo[2];
    cping[0] = (float*)alloc(NH * 4);
    cping[1] = (float*)alloc(NH * 4);
    hhi[0]   = (unsigned short*)alloc(NH * 2);
    hhi[1]   = (unsigned short*)alloc(NH * 2);
    hlo[0]   = (unsigned short*)alloc(NH * 2);
    hlo[1]   = (unsigned short*)alloc(NH * 2);
    unsigned short* hs_hi  = (unsigned short*)alloc((size_t)DSTEPS * NH * 2);
    unsigned short* hs_lo  = (unsigned short*)alloc((size_t)DSTEPS * NH * 2);
    unsigned short* Wenc_h = (unsigned short*)alloc((size_t)GATES * 576 * 2);
    unsigned short* Wenc_l = (unsigned short*)alloc((size_t)GATES * 576 * 2);
    unsigned short* Wdec_h = (unsigned short*)alloc((size_t)GATES * 512 * 2);
    unsigned short* Wdec_l = (unsigned short*)alloc((size_t)GATES * 512 * 2);

    // Weight prep (runs every call; deterministic)
    prep_weights<<<dim3(GATES), dim3(256), 0, stream>>>(W_hh_e, W_ih_e, 576, Wenc_h, Wenc_l);
    prep_weights<<<dim3(GATES), dim3(256), 0, stream>>>(W_hh_d, nullptr, 512, Wdec_h, Wdec_l);

    // Zero initial state
    hipMemsetAsync(hhi[0], 0, NH * 2, stream);
    hipMemsetAsync(hlo[0], 0, NH * 2, stream);
    hipMemsetAsync(cping[0], 0, NH * 4, stream);

    dim3 grid(32, 8), block(256);

    // Encoder: 168 steps; even count -> final state lands back in slot 0.
    for (int t = 0; t < TD; ++t) {
        lstm_step_mfma<1><<<grid, block, 0, stream>>>(
            hhi[t & 1], hlo[t & 1], cping[t & 1],
            Wenc_h, Wenc_l, b_e, x, t,
            hhi[(t + 1) & 1], hlo[(t + 1) & 1], cping[(t + 1) & 1]);
    }

    // Decoder: c starts at zero, h starts at h_enc (slot 0); h_out -> hs planes.
    hipMemsetAsync(cping[0], 0, NH * 4, stream);
    for (int s = 0; s < DSTEPS; ++s) {
        const unsigned short* hih = (s == 0) ? hhi[0] : hs_hi + (size_t)(s - 1) * NH;
        const unsigned short* hil = (s == 0) ? hlo[0] : hs_lo + (size_t)(s - 1) * NH;
        lstm_step_mfma<0><<<grid, block, 0, stream>>>(
            hih, hil, cping[s & 1],
            Wdec_h, Wdec_l, b_d, nullptr, 0,
            hs_hi + (size_t)s * NH, hs_lo + (size_t)s * NH, cping[(s + 1) & 1]);
    }

    dense_kernel<<<dim3(NB / 64, DSTEPS), dim3(256), 0, stream>>>(
        hs_hi, hs_lo, W_dense, b_dense, out);
}